// Round 8
// baseline (97.584 us; speedup 1.0000x reference)
//
#include <hip/hip_runtime.h>

// ReactionTerm v6: R7 + software-pipelined rate stream.
// R7 post-mortem: __syncthreads() drains vmcnt at every phase boundary, so
// the 5 segment-sum loops (~16us LDS-only) leave HBM idle, and chunk c+1's
// 256MB-stream loads can't issue until sum c is done. R8: relaxed barriers
// (lgkmcnt(0)-only + raw s_barrier) keep global loads in flight across
// barriers; rate vectors double-buffered in named registers (qA/qB), issued
// right after the previous compute so they stream during the sum phase.
// Geometry: B=4096, S=1024, N1=4096, N2=16384.

#define SWL(k) ((k) ^ (((k) >> 3) & 7))

// LDS-only barrier: orders LDS ops, leaves VMEM loads in flight.
#define LDS_BARRIER()                                          \
    do {                                                       \
        asm volatile("s_waitcnt lgkmcnt(0)" ::: "memory");     \
        __builtin_amdgcn_s_barrier();                          \
    } while (0)

// ---------- setup: 5 blocks (0: phase1; 1..4: phase2 chunk) ------------------
__global__ __launch_bounds__(1024) void setup_kernel(
    const int* __restrict__ i1p, const int* __restrict__ i2p,
    unsigned short* __restrict__ pos1, unsigned short* __restrict__ pos2,
    unsigned* __restrict__ segpack) {
    __shared__ int h[1024];
    __shared__ int c[1024];
    const int tid = threadIdx.x;
    const int ph  = blockIdx.x;  // 0: first-order; 1..4: second-order chunk ph-1
    const int* __restrict__ ip = (ph == 0) ? i1p : (i2p + (ph - 1) * 4096);
    unsigned short* __restrict__ pos = (ph == 0) ? pos1 : (pos2 + (ph - 1) * 4096);

    h[tid] = 0;
    __syncthreads();
#pragma unroll
    for (int j = 0; j < 4; ++j) atomicAdd(&h[ip[j * 1024 + tid]], 1);
    __syncthreads();
    int n = h[tid];
    c[tid] = n;
    __syncthreads();
    for (int d = 1; d < 1024; d <<= 1) {
        int t = (tid >= d) ? c[tid - d] : 0;
        __syncthreads();
        if (tid >= d) c[tid] += t;
        __syncthreads();
    }
    int start = c[tid] - n;  // exclusive scan
    segpack[ph * 1024 + tid] = (unsigned)start | ((unsigned)n << 16);
    __syncthreads();
    c[tid] = start;          // reuse as cursor
    __syncthreads();
#pragma unroll
    for (int j = 0; j < 4; ++j) {
        int idx = j * 1024 + tid;
        int p = atomicAdd(&c[ip[idx]], 1);           // ds_add_rtn_u32
        pos[idx] = (unsigned short)SWL(p);           // swizzle baked in
    }
}

// ---------- main: 4 rows/block, 1024 threads, pipelined ----------------------
__global__ __launch_bounds__(1024) void reaction_gather4(
    const float* __restrict__ y_in, const float* __restrict__ rate_1,
    const float* __restrict__ rate_2,
    const int* __restrict__ i1r, const int* __restrict__ i2r,
    const unsigned short* __restrict__ pos1, const unsigned short* __restrict__ pos2,
    const unsigned* __restrict__ segpack,
    float* __restrict__ y_out) {
    __shared__ float4 y_s[1024];  // 16 KB
    __shared__ float4 buf[4096];  // 64 KB swizzled sorted products (4 rows)

    const int tid = threadIdx.x;
    const long b0 = (long)blockIdx.x * 4;
    const float* __restrict__ r1b = rate_1 + b0 * 4096;
    const float* __restrict__ r2b = rate_2 + b0 * 16384;
    const int4* __restrict__ i2r4 = (const int4*)i2r;

    // ---- issue ph1 rate loads (stage A) ----
    float4 qA0 = ((const float4*)(r1b         ))[tid];
    float4 qA1 = ((const float4*)(r1b +  4096))[tid];
    float4 qA2 = ((const float4*)(r1b +  8192))[tid];
    float4 qA3 = ((const float4*)(r1b + 12288))[tid];

    // ---- stage y rows ----
    {
        float v0 = y_in[(b0 + 0) * 1024 + tid];
        float v1 = y_in[(b0 + 1) * 1024 + tid];
        float v2 = y_in[(b0 + 2) * 1024 + tid];
        float v3 = y_in[(b0 + 3) * 1024 + tid];
        y_s[tid] = make_float4(v0, v1, v2, v3);
    }

    // ---- issue chunk-0 rate loads (stage B) before first barrier ----
    float4 qB0 = ((const float4*)(r2b         ))[tid];
    float4 qB1 = ((const float4*)(r2b + 16384))[tid];
    float4 qB2 = ((const float4*)(r2b + 32768))[tid];
    float4 qB3 = ((const float4*)(r2b + 49152))[tid];

    LDS_BARRIER();  // y_s ready; qB still in flight

    float4 acc = make_float4(0.f, 0.f, 0.f, 0.f);

    // ---- phase-1 products (uses qA) ----
    {
        int4    ia = ((const int4*)i1r)[tid];
        ushort4 p  = ((const ushort4*)pos1)[tid];
        float4 y;
        y = y_s[ia.x]; buf[p.x] = make_float4(y.x*qA0.x, y.y*qA1.x, y.z*qA2.x, y.w*qA3.x);
        y = y_s[ia.y]; buf[p.y] = make_float4(y.x*qA0.y, y.y*qA1.y, y.z*qA2.y, y.w*qA3.y);
        y = y_s[ia.z]; buf[p.z] = make_float4(y.x*qA0.z, y.y*qA1.z, y.z*qA2.z, y.w*qA3.z);
        y = y_s[ia.w]; buf[p.w] = make_float4(y.x*qA0.w, y.y*qA1.w, y.z*qA2.w, y.w*qA3.w);
    }
    // ---- issue chunk-1 rate loads (stage A, reusing regs) ----
    qA0 = ((const float4*)(r2b +  4096         ))[tid];
    qA1 = ((const float4*)(r2b +  4096 + 16384))[tid];
    qA2 = ((const float4*)(r2b +  4096 + 32768))[tid];
    qA3 = ((const float4*)(r2b +  4096 + 49152))[tid];

    LDS_BARRIER();  // buf ready; loads in flight
    {   // sum ph1
        unsigned sp = segpack[tid];
        int s = (int)(sp & 0xffffu), e = s + (int)(sp >> 16);
        for (int k = s; k < e; ++k) {
            float4 v = buf[SWL(k)];
            acc.x += v.x; acc.y += v.y; acc.z += v.z; acc.w += v.w;
        }
    }
    LDS_BARRIER();  // buf consumed

#define PH2_COMPUTE(CB, Q0, Q1, Q2, Q3)                                            \
    {                                                                              \
        int4    e0 = i2r4[(CB) / 2 + 2 * tid];                                     \
        int4    e1 = i2r4[(CB) / 2 + 2 * tid + 1];                                 \
        ushort4 pp = ((const ushort4*)(pos2 + (CB)))[tid];                         \
        float4 ya, yb;                                                             \
        ya = y_s[e0.x]; yb = y_s[e0.y];                                            \
        buf[pp.x] = make_float4(ya.x*yb.x*Q0.x, ya.y*yb.y*Q1.x,                    \
                                ya.z*yb.z*Q2.x, ya.w*yb.w*Q3.x);                   \
        ya = y_s[e0.z]; yb = y_s[e0.w];                                            \
        buf[pp.y] = make_float4(ya.x*yb.x*Q0.y, ya.y*yb.y*Q1.y,                    \
                                ya.z*yb.z*Q2.y, ya.w*yb.w*Q3.y);                   \
        ya = y_s[e1.x]; yb = y_s[e1.y];                                            \
        buf[pp.z] = make_float4(ya.x*yb.x*Q0.z, ya.y*yb.y*Q1.z,                    \
                                ya.z*yb.z*Q2.z, ya.w*yb.w*Q3.z);                   \
        ya = y_s[e1.z]; yb = y_s[e1.w];                                            \
        buf[pp.w] = make_float4(ya.x*yb.x*Q0.w, ya.y*yb.y*Q1.w,                    \
                                ya.z*yb.z*Q2.w, ya.w*yb.w*Q3.w);                   \
    }

#define SEG_SUM(PH)                                                                \
    {                                                                              \
        unsigned sp = segpack[(PH) * 1024 + tid];                                  \
        int s = (int)(sp & 0xffffu), e = s + (int)(sp >> 16);                      \
        for (int k = s; k < e; ++k) {                                              \
            float4 v = buf[SWL(k)];                                                \
            acc.x += v.x; acc.y += v.y; acc.z += v.z; acc.w += v.w;                \
        }                                                                          \
    }

    // ---- chunk 0: compute from qB; issue chunk 2 into qB after ----
    PH2_COMPUTE(0 * 4096, qB0, qB1, qB2, qB3);
    qB0 = ((const float4*)(r2b + 8192         ))[tid];
    qB1 = ((const float4*)(r2b + 8192 + 16384))[tid];
    qB2 = ((const float4*)(r2b + 8192 + 32768))[tid];
    qB3 = ((const float4*)(r2b + 8192 + 49152))[tid];
    LDS_BARRIER();
    SEG_SUM(1);
    LDS_BARRIER();

    // ---- chunk 1: compute from qA; issue chunk 3 into qA ----
    PH2_COMPUTE(1 * 4096, qA0, qA1, qA2, qA3);
    qA0 = ((const float4*)(r2b + 12288         ))[tid];
    qA1 = ((const float4*)(r2b + 12288 + 16384))[tid];
    qA2 = ((const float4*)(r2b + 12288 + 32768))[tid];
    qA3 = ((const float4*)(r2b + 12288 + 49152))[tid];
    LDS_BARRIER();
    SEG_SUM(2);
    LDS_BARRIER();

    // ---- chunk 2: compute from qB ----
    PH2_COMPUTE(2 * 4096, qB0, qB1, qB2, qB3);
    LDS_BARRIER();
    SEG_SUM(3);
    LDS_BARRIER();

    // ---- chunk 3: compute from qA ----
    PH2_COMPUTE(3 * 4096, qA0, qA1, qA2, qA3);
    LDS_BARRIER();
    SEG_SUM(4);

    y_out[(b0 + 0) * 1024 + tid] = acc.x;
    y_out[(b0 + 1) * 1024 + tid] = acc.y;
    y_out[(b0 + 2) * 1024 + tid] = acc.z;
    y_out[(b0 + 3) * 1024 + tid] = acc.w;
#undef PH2_COMPUTE
#undef SEG_SUM
}

// ---------- Fallback (generic sizes) ------------------------------------------
template <int BLOCK>
__global__ __launch_bounds__(BLOCK) void reaction_fallback(
    const float* __restrict__ y_in, const float* __restrict__ rate_1,
    const float* __restrict__ rate_2, const int* __restrict__ inds_1r,
    const int* __restrict__ inds_1p, const int* __restrict__ inds_2r,
    const int* __restrict__ inds_2p, float* __restrict__ y_out,
    int S, int N1, int N2) {
    extern __shared__ float smem[];
    float* y_s = smem;
    float* acc = smem + S;
    const int b = blockIdx.x, tid = threadIdx.x;
    const float* yrow = y_in + (size_t)b * S;
    for (int i = tid; i < S; i += BLOCK) { y_s[i] = yrow[i]; acc[i] = 0.f; }
    __syncthreads();
    const float* r1 = rate_1 + (size_t)b * N1;
    for (int i = tid; i < N1; i += BLOCK)
        atomicAdd(&acc[inds_1p[i]], y_s[inds_1r[i]] * r1[i]);
    const float* r2 = rate_2 + (size_t)b * N2;
    for (int i = tid; i < N2; i += BLOCK)
        atomicAdd(&acc[inds_2p[i]], y_s[inds_2r[2 * i]] * y_s[inds_2r[2 * i + 1]] * r2[i]);
    __syncthreads();
    float* orow = y_out + (size_t)b * S;
    for (int i = tid; i < S; i += BLOCK) orow[i] = acc[i];
}

extern "C" void kernel_launch(void* const* d_in, const int* in_sizes, int n_in,
                              void* d_out, int out_size, void* d_ws, size_t ws_size,
                              hipStream_t stream) {
    const float* y_in    = (const float*)d_in[0];
    const float* rate_1  = (const float*)d_in[1];
    const float* rate_2  = (const float*)d_in[2];
    const int*   inds_1r = (const int*)d_in[3];
    const int*   inds_1p = (const int*)d_in[4];
    const int*   inds_2r = (const int*)d_in[5];
    const int*   inds_2p = (const int*)d_in[6];
    float*       y_out   = (float*)d_out;

    const int N1 = in_sizes[3];           // 4096
    const int N2 = in_sizes[6];           // 16384
    const int B  = in_sizes[1] / N1;      // 4096
    const int S  = in_sizes[0] / B;       // 1024

    const bool specialized = (S == 1024 && N1 == 4096 && N2 == 16384 &&
                              (B % 4) == 0 && ws_size >= (size_t)(60 * 1024));
    if (!specialized) {
        size_t smem = (size_t)2 * S * sizeof(float);
        reaction_fallback<256><<<B, 256, smem, stream>>>(
            y_in, rate_1, rate_2, inds_1r, inds_1p, inds_2r, inds_2p,
            y_out, S, N1, N2);
        return;
    }

    // Workspace:
    //   segpack : 5120 u32  [ 0K, 20K)  (ph1 + 4 ph2 chunks; start | n<<16)
    //   pos1    : 4096 u16  [20K, 28K)  (swizzled positions)
    //   pos2    : 16384 u16 [28K, 60K)  (chunk-local swizzled positions)
    char* ws = (char*)d_ws;
    unsigned*       segpack = (unsigned*)(ws + 0);
    unsigned short* pos1    = (unsigned short*)(ws + 20 * 1024);
    unsigned short* pos2    = (unsigned short*)(ws + 28 * 1024);

    setup_kernel<<<5, 1024, 0, stream>>>(inds_1p, inds_2p, pos1, pos2, segpack);
    reaction_gather4<<<B / 4, 1024, 0, stream>>>(y_in, rate_1, rate_2,
                                                 inds_1r, inds_2r, pos1, pos2,
                                                 segpack, y_out);
}

// Round 9
// 81.725 us; speedup vs baseline: 1.1940x; 1.1940x over previous
//
#include <hip/hip_runtime.h>

// ReactionTerm v7: R7 (proven 80.8us) + block-parity phase rotation.
// R8 post-mortem: register double-buffering (32 VGPRs live across barriers)
// pushed VGPR>64 -> 1 block/CU instead of 2 -> regression. Reverted.
// R9: phases are independent (each fully overwrites buf), so half the blocks
// run the 5-phase sequence rotated by 2. At any instant ~half the resident
// blocks are in load-heavy product phases while half are in LDS-only sum
// phases -> HBM demand is smoothed instead of phase-locked bursts.
// Geometry: B=4096, S=1024, N1=4096, N2=16384.

#define SWL(k) ((k) ^ (((k) >> 3) & 7))

// ---------- setup: 5 blocks (0: phase1; 1..4: phase2 chunk) ------------------
__global__ __launch_bounds__(1024) void setup_kernel(
    const int* __restrict__ i1p, const int* __restrict__ i2p,
    unsigned short* __restrict__ pos1, unsigned short* __restrict__ pos2,
    unsigned* __restrict__ segpack) {
    __shared__ int h[1024];
    __shared__ int c[1024];
    const int tid = threadIdx.x;
    const int ph  = blockIdx.x;  // 0: first-order; 1..4: second-order chunk ph-1
    const int* __restrict__ ip = (ph == 0) ? i1p : (i2p + (ph - 1) * 4096);
    unsigned short* __restrict__ pos = (ph == 0) ? pos1 : (pos2 + (ph - 1) * 4096);

    h[tid] = 0;
    __syncthreads();
#pragma unroll
    for (int j = 0; j < 4; ++j) atomicAdd(&h[ip[j * 1024 + tid]], 1);
    __syncthreads();
    int n = h[tid];
    c[tid] = n;
    __syncthreads();
    for (int d = 1; d < 1024; d <<= 1) {
        int t = (tid >= d) ? c[tid - d] : 0;
        __syncthreads();
        if (tid >= d) c[tid] += t;
        __syncthreads();
    }
    int start = c[tid] - n;  // exclusive scan
    segpack[ph * 1024 + tid] = (unsigned)start | ((unsigned)n << 16);
    __syncthreads();
    c[tid] = start;          // reuse as cursor
    __syncthreads();
#pragma unroll
    for (int j = 0; j < 4; ++j) {
        int idx = j * 1024 + tid;
        int p = atomicAdd(&c[ip[idx]], 1);           // ds_add_rtn_u32
        pos[idx] = (unsigned short)SWL(p);           // swizzle baked in
    }
}

// ---------- main: 4 rows/block, 1024 threads ---------------------------------
__global__ __launch_bounds__(1024, 4) void reaction_gather4(
    const float* __restrict__ y_in, const float* __restrict__ rate_1,
    const float* __restrict__ rate_2,
    const int* __restrict__ i1r, const int* __restrict__ i2r,
    const unsigned short* __restrict__ pos1, const unsigned short* __restrict__ pos2,
    const unsigned* __restrict__ segpack,
    float* __restrict__ y_out) {
    __shared__ float4 y_s[1024];  // 16 KB
    __shared__ float4 buf[4096];  // 64 KB swizzled sorted products (4 rows)

    const int tid = threadIdx.x;
    const long b0 = (long)blockIdx.x * 4;
    const float* __restrict__ r1b = rate_1 + b0 * 4096;
    const float* __restrict__ r2b = rate_2 + b0 * 16384;
    const int4* __restrict__ i2r4 = (const int4*)i2r;

    // stage 4 y rows (coalesced per row)
    {
        float v0 = y_in[(b0 + 0) * 1024 + tid];
        float v1 = y_in[(b0 + 1) * 1024 + tid];
        float v2 = y_in[(b0 + 2) * 1024 + tid];
        float v3 = y_in[(b0 + 3) * 1024 + tid];
        y_s[tid] = make_float4(v0, v1, v2, v3);
    }
    __syncthreads();

    float4 acc = make_float4(0.f, 0.f, 0.f, 0.f);

#define PH1_COMPUTE()                                                              \
    {                                                                              \
        int4    ia = ((const int4*)i1r)[tid];                                      \
        ushort4 p  = ((const ushort4*)pos1)[tid];                                  \
        float4 q0 = ((const float4*)(r1b         ))[tid];                          \
        float4 q1 = ((const float4*)(r1b +  4096))[tid];                           \
        float4 q2 = ((const float4*)(r1b +  8192))[tid];                           \
        float4 q3 = ((const float4*)(r1b + 12288))[tid];                           \
        float4 y;                                                                  \
        y = y_s[ia.x]; buf[p.x] = make_float4(y.x*q0.x, y.y*q1.x, y.z*q2.x, y.w*q3.x); \
        y = y_s[ia.y]; buf[p.y] = make_float4(y.x*q0.y, y.y*q1.y, y.z*q2.y, y.w*q3.y); \
        y = y_s[ia.z]; buf[p.z] = make_float4(y.x*q0.z, y.y*q1.z, y.z*q2.z, y.w*q3.z); \
        y = y_s[ia.w]; buf[p.w] = make_float4(y.x*q0.w, y.y*q1.w, y.z*q2.w, y.w*q3.w); \
    }

#define PH2_COMPUTE(C)                                                             \
    {                                                                              \
        const int cb = (C) * 4096;                                                 \
        int4    e0 = i2r4[cb / 2 + 2 * tid];                                       \
        int4    e1 = i2r4[cb / 2 + 2 * tid + 1];                                   \
        ushort4 pp = ((const ushort4*)(pos2 + cb))[tid];                           \
        float4  q0 = ((const float4*)(r2b + cb         ))[tid];                    \
        float4  q1 = ((const float4*)(r2b + cb + 16384))[tid];                     \
        float4  q2 = ((const float4*)(r2b + cb + 32768))[tid];                     \
        float4  q3 = ((const float4*)(r2b + cb + 49152))[tid];                     \
        float4 ya, yb;                                                             \
        ya = y_s[e0.x]; yb = y_s[e0.y];                                            \
        buf[pp.x] = make_float4(ya.x*yb.x*q0.x, ya.y*yb.y*q1.x,                    \
                                ya.z*yb.z*q2.x, ya.w*yb.w*q3.x);                   \
        ya = y_s[e0.z]; yb = y_s[e0.w];                                            \
        buf[pp.y] = make_float4(ya.x*yb.x*q0.y, ya.y*yb.y*q1.y,                    \
                                ya.z*yb.z*q2.y, ya.w*yb.w*q3.y);                   \
        ya = y_s[e1.x]; yb = y_s[e1.y];                                            \
        buf[pp.z] = make_float4(ya.x*yb.x*q0.z, ya.y*yb.y*q1.z,                    \
                                ya.z*yb.z*q2.z, ya.w*yb.w*q3.z);                   \
        ya = y_s[e1.z]; yb = y_s[e1.w];                                            \
        buf[pp.w] = make_float4(ya.x*yb.x*q0.w, ya.y*yb.y*q1.w,                    \
                                ya.z*yb.z*q2.w, ya.w*yb.w*q3.w);                   \
    }

#define SEG_SUM(PH)                                                                \
    {                                                                              \
        unsigned sp = segpack[(PH) * 1024 + tid];                                  \
        int s = (int)(sp & 0xffffu), e = s + (int)(sp >> 16);                      \
        for (int k = s; k < e; ++k) {                                              \
            float4 v = buf[SWL(k)];                                                \
            acc.x += v.x; acc.y += v.y; acc.z += v.z; acc.w += v.w;                \
        }                                                                          \
    }

#define B_ __syncthreads()

    // Phase rotation: half the blocks start at chunk 2 so load-heavy and
    // LDS-sum phases interleave across the chip (and across co-resident pairs
    // under the likely n%256 dispatch pattern).
    const bool rot = ((blockIdx.x ^ (blockIdx.x >> 8)) & 1) != 0;
    if (!rot) {
        PH1_COMPUTE();  B_; SEG_SUM(0); B_;
        PH2_COMPUTE(0); B_; SEG_SUM(1); B_;
        PH2_COMPUTE(1); B_; SEG_SUM(2); B_;
        PH2_COMPUTE(2); B_; SEG_SUM(3); B_;
        PH2_COMPUTE(3); B_; SEG_SUM(4);
    } else {
        PH2_COMPUTE(2); B_; SEG_SUM(3); B_;
        PH2_COMPUTE(3); B_; SEG_SUM(4); B_;
        PH1_COMPUTE();  B_; SEG_SUM(0); B_;
        PH2_COMPUTE(0); B_; SEG_SUM(1); B_;
        PH2_COMPUTE(1); B_; SEG_SUM(2);
    }

    y_out[(b0 + 0) * 1024 + tid] = acc.x;
    y_out[(b0 + 1) * 1024 + tid] = acc.y;
    y_out[(b0 + 2) * 1024 + tid] = acc.z;
    y_out[(b0 + 3) * 1024 + tid] = acc.w;
#undef PH1_COMPUTE
#undef PH2_COMPUTE
#undef SEG_SUM
#undef B_
}

// ---------- Fallback (generic sizes) ------------------------------------------
template <int BLOCK>
__global__ __launch_bounds__(BLOCK) void reaction_fallback(
    const float* __restrict__ y_in, const float* __restrict__ rate_1,
    const float* __restrict__ rate_2, const int* __restrict__ inds_1r,
    const int* __restrict__ inds_1p, const int* __restrict__ inds_2r,
    const int* __restrict__ inds_2p, float* __restrict__ y_out,
    int S, int N1, int N2) {
    extern __shared__ float smem[];
    float* y_s = smem;
    float* acc = smem + S;
    const int b = blockIdx.x, tid = threadIdx.x;
    const float* yrow = y_in + (size_t)b * S;
    for (int i = tid; i < S; i += BLOCK) { y_s[i] = yrow[i]; acc[i] = 0.f; }
    __syncthreads();
    const float* r1 = rate_1 + (size_t)b * N1;
    for (int i = tid; i < N1; i += BLOCK)
        atomicAdd(&acc[inds_1p[i]], y_s[inds_1r[i]] * r1[i]);
    const float* r2 = rate_2 + (size_t)b * N2;
    for (int i = tid; i < N2; i += BLOCK)
        atomicAdd(&acc[inds_2p[i]], y_s[inds_2r[2 * i]] * y_s[inds_2r[2 * i + 1]] * r2[i]);
    __syncthreads();
    float* orow = y_out + (size_t)b * S;
    for (int i = tid; i < S; i += BLOCK) orow[i] = acc[i];
}

extern "C" void kernel_launch(void* const* d_in, const int* in_sizes, int n_in,
                              void* d_out, int out_size, void* d_ws, size_t ws_size,
                              hipStream_t stream) {
    const float* y_in    = (const float*)d_in[0];
    const float* rate_1  = (const float*)d_in[1];
    const float* rate_2  = (const float*)d_in[2];
    const int*   inds_1r = (const int*)d_in[3];
    const int*   inds_1p = (const int*)d_in[4];
    const int*   inds_2r = (const int*)d_in[5];
    const int*   inds_2p = (const int*)d_in[6];
    float*       y_out   = (float*)d_out;

    const int N1 = in_sizes[3];           // 4096
    const int N2 = in_sizes[6];           // 16384
    const int B  = in_sizes[1] / N1;      // 4096
    const int S  = in_sizes[0] / B;       // 1024

    const bool specialized = (S == 1024 && N1 == 4096 && N2 == 16384 &&
                              (B % 4) == 0 && ws_size >= (size_t)(60 * 1024));
    if (!specialized) {
        size_t smem = (size_t)2 * S * sizeof(float);
        reaction_fallback<256><<<B, 256, smem, stream>>>(
            y_in, rate_1, rate_2, inds_1r, inds_1p, inds_2r, inds_2p,
            y_out, S, N1, N2);
        return;
    }

    // Workspace:
    //   segpack : 5120 u32  [ 0K, 20K)  (ph1 + 4 ph2 chunks; start | n<<16)
    //   pos1    : 4096 u16  [20K, 28K)  (swizzled positions)
    //   pos2    : 16384 u16 [28K, 60K)  (chunk-local swizzled positions)
    char* ws = (char*)d_ws;
    unsigned*       segpack = (unsigned*)(ws + 0);
    unsigned short* pos1    = (unsigned short*)(ws + 20 * 1024);
    unsigned short* pos2    = (unsigned short*)(ws + 28 * 1024);

    setup_kernel<<<5, 1024, 0, stream>>>(inds_1p, inds_2p, pos1, pos2, segpack);
    reaction_gather4<<<B / 4, 1024, 0, stream>>>(y_in, rate_1, rate_2,
                                                 inds_1r, inds_2r, pos1, pos2,
                                                 segpack, y_out);
}

// Round 10
// 81.250 us; speedup vs baseline: 1.2010x; 1.0058x over previous
//
#include <hip/hip_runtime.h>

// ReactionTerm v8: single-barrier mixed regions, double-buffered half-chunks.
// R9 lesson: cross-block phase rotation neutral -> the exposed time is the
// LDS-only sum phases inside each block (HBM idles there). R10: 10 chunks of
// 2048 terms; buf = 2 x 2048 float4 halves (64 KB); each region does
// {issue chunk-r loads | sum chunk r-1 | write products r} then ONE
// __syncthreads(). Loads are consumed in-region (no live-across-barrier regs,
// the R8 trap); sum(r-1) and write(r) touch opposite halves.
// LDS 80 KB -> 2 blocks/CU enforced via __launch_bounds__(1024, 8).
// Geometry: B=4096, S=1024, N1=4096, N2=16384.

#define SWL(k) ((k) ^ (((k) >> 3) & 7))

// ---------- setup: 10 blocks, one per 2048-term chunk ------------------------
// chunks 0..1 = first-order halves; chunks 2..9 = second-order eighths.
__global__ __launch_bounds__(1024) void setup_kernel(
    const int* __restrict__ i1p, const int* __restrict__ i2p,
    unsigned short* __restrict__ pos1, unsigned short* __restrict__ pos2,
    unsigned* __restrict__ segpack) {
    __shared__ int h[1024];
    __shared__ int c[1024];
    const int tid = threadIdx.x;
    const int ch  = blockIdx.x;
    const int* __restrict__ ip = (ch < 2) ? (i1p + ch * 2048)
                                          : (i2p + (ch - 2) * 2048);
    unsigned short* __restrict__ pos = (ch < 2) ? (pos1 + ch * 2048)
                                                : (pos2 + (ch - 2) * 2048);

    h[tid] = 0;
    __syncthreads();
    const int t0 = ip[2 * tid], t1 = ip[2 * tid + 1];
    atomicAdd(&h[t0], 1);
    atomicAdd(&h[t1], 1);
    __syncthreads();
    int n = h[tid];
    c[tid] = n;
    __syncthreads();
    for (int d = 1; d < 1024; d <<= 1) {
        int t = (tid >= d) ? c[tid - d] : 0;
        __syncthreads();
        if (tid >= d) c[tid] += t;
        __syncthreads();
    }
    int start = c[tid] - n;  // exclusive scan, < 2048
    segpack[ch * 1024 + tid] = (unsigned)start | ((unsigned)n << 16);
    __syncthreads();
    c[tid] = start;          // reuse as cursor
    __syncthreads();
    int p0 = atomicAdd(&c[t0], 1);
    int p1 = atomicAdd(&c[t1], 1);
    pos[2 * tid]     = (unsigned short)SWL(p0);   // swizzle baked in
    pos[2 * tid + 1] = (unsigned short)SWL(p1);
}

// ---------- main: 4 rows/block, 1024 threads, 1 barrier per region -----------
__global__ __launch_bounds__(1024, 8) void reaction_gather4(
    const float* __restrict__ y_in, const float* __restrict__ rate_1,
    const float* __restrict__ rate_2,
    const int* __restrict__ i1r, const int* __restrict__ i2r,
    const unsigned short* __restrict__ pos1, const unsigned short* __restrict__ pos2,
    const unsigned* __restrict__ segpack,
    float* __restrict__ y_out) {
    __shared__ float4 y_s[1024];     // 16 KB
    __shared__ float4 buf[2][2048];  // 64 KB: double-buffered product halves

    const int tid = threadIdx.x;
    const long b0 = (long)blockIdx.x * 4;
    const float* __restrict__ r1b = rate_1 + b0 * 4096;
    const float* __restrict__ r2b = rate_2 + b0 * 16384;

    float4 acc = make_float4(0.f, 0.f, 0.f, 0.f);

    // Loads for a chunk (issued first in each region, consumed at region end).
#define LOAD_PH1(C)                                                            \
    int2     ia = ((const int2*)(i1r + (C) * 2048))[tid];                      \
    unsigned pp = ((const unsigned*)(pos1 + (C) * 2048))[tid];                 \
    float2 q0 = ((const float2*)(r1b + (C) * 2048         ))[tid];             \
    float2 q1 = ((const float2*)(r1b + (C) * 2048 +  4096))[tid];              \
    float2 q2 = ((const float2*)(r1b + (C) * 2048 +  8192))[tid];              \
    float2 q3 = ((const float2*)(r1b + (C) * 2048 + 12288))[tid];

#define WRITE_PH1(P)                                                           \
    {                                                                          \
        unsigned pa = pp & 0xffffu, pb = pp >> 16;                             \
        float4 y;                                                              \
        y = y_s[ia.x];                                                         \
        buf[P][pa] = make_float4(y.x*q0.x, y.y*q1.x, y.z*q2.x, y.w*q3.x);      \
        y = y_s[ia.y];                                                         \
        buf[P][pb] = make_float4(y.x*q0.y, y.y*q1.y, y.z*q2.y, y.w*q3.y);      \
    }

#define LOAD_PH2(C)                                                            \
    int4     e  = ((const int4*)i2r)[(C) * 1024 + tid];                        \
    unsigned pp = ((const unsigned*)(pos2 + (C) * 2048))[tid];                 \
    float2 q0 = ((const float2*)(r2b + (C) * 2048         ))[tid];             \
    float2 q1 = ((const float2*)(r2b + (C) * 2048 + 16384))[tid];              \
    float2 q2 = ((const float2*)(r2b + (C) * 2048 + 32768))[tid];              \
    float2 q3 = ((const float2*)(r2b + (C) * 2048 + 49152))[tid];

#define WRITE_PH2(P)                                                           \
    {                                                                          \
        unsigned pa = pp & 0xffffu, pb = pp >> 16;                             \
        float4 ya, yb;                                                         \
        ya = y_s[e.x]; yb = y_s[e.y];                                          \
        buf[P][pa] = make_float4(ya.x*yb.x*q0.x, ya.y*yb.y*q1.x,               \
                                 ya.z*yb.z*q2.x, ya.w*yb.w*q3.x);              \
        ya = y_s[e.z]; yb = y_s[e.w];                                          \
        buf[P][pb] = make_float4(ya.x*yb.x*q0.y, ya.y*yb.y*q1.y,               \
                                 ya.z*yb.z*q2.y, ya.w*yb.w*q3.y);              \
    }

#define SUM(CH, P)                                                             \
    {                                                                          \
        unsigned sp = segpack[(CH) * 1024 + tid];                              \
        int s = (int)(sp & 0xffffu), n = (int)(sp >> 16);                      \
        for (int k = s; k < s + n; ++k) {                                      \
            float4 v = buf[P][SWL(k)];                                         \
            acc.x += v.x; acc.y += v.y; acc.z += v.z; acc.w += v.w;            \
        }                                                                      \
    }

#define B_ __syncthreads()

    // Prologue: issue chunk-0 loads, stage y, then write products 0.
    {
        LOAD_PH1(0)
        {
            float v0 = y_in[(b0 + 0) * 1024 + tid];
            float v1 = y_in[(b0 + 1) * 1024 + tid];
            float v2 = y_in[(b0 + 2) * 1024 + tid];
            float v3 = y_in[(b0 + 3) * 1024 + tid];
            y_s[tid] = make_float4(v0, v1, v2, v3);
        }
        B_;  // y_s ready
        WRITE_PH1(0)
    }
    B_;
    { LOAD_PH1(1) SUM(0, 0) WRITE_PH1(1) }  B_;   // global chunk 1
    { LOAD_PH2(0) SUM(1, 1) WRITE_PH2(0) }  B_;   // global chunk 2
    { LOAD_PH2(1) SUM(2, 0) WRITE_PH2(1) }  B_;
    { LOAD_PH2(2) SUM(3, 1) WRITE_PH2(0) }  B_;
    { LOAD_PH2(3) SUM(4, 0) WRITE_PH2(1) }  B_;
    { LOAD_PH2(4) SUM(5, 1) WRITE_PH2(0) }  B_;
    { LOAD_PH2(5) SUM(6, 0) WRITE_PH2(1) }  B_;
    { LOAD_PH2(6) SUM(7, 1) WRITE_PH2(0) }  B_;
    { LOAD_PH2(7) SUM(8, 0) WRITE_PH2(1) }  B_;
    SUM(9, 1)

    y_out[(b0 + 0) * 1024 + tid] = acc.x;
    y_out[(b0 + 1) * 1024 + tid] = acc.y;
    y_out[(b0 + 2) * 1024 + tid] = acc.z;
    y_out[(b0 + 3) * 1024 + tid] = acc.w;

#undef LOAD_PH1
#undef WRITE_PH1
#undef LOAD_PH2
#undef WRITE_PH2
#undef SUM
#undef B_
}

// ---------- Fallback (generic sizes) ------------------------------------------
template <int BLOCK>
__global__ __launch_bounds__(BLOCK) void reaction_fallback(
    const float* __restrict__ y_in, const float* __restrict__ rate_1,
    const float* __restrict__ rate_2, const int* __restrict__ inds_1r,
    const int* __restrict__ inds_1p, const int* __restrict__ inds_2r,
    const int* __restrict__ inds_2p, float* __restrict__ y_out,
    int S, int N1, int N2) {
    extern __shared__ float smem[];
    float* y_s = smem;
    float* acc = smem + S;
    const int b = blockIdx.x, tid = threadIdx.x;
    const float* yrow = y_in + (size_t)b * S;
    for (int i = tid; i < S; i += BLOCK) { y_s[i] = yrow[i]; acc[i] = 0.f; }
    __syncthreads();
    const float* r1 = rate_1 + (size_t)b * N1;
    for (int i = tid; i < N1; i += BLOCK)
        atomicAdd(&acc[inds_1p[i]], y_s[inds_1r[i]] * r1[i]);
    const float* r2 = rate_2 + (size_t)b * N2;
    for (int i = tid; i < N2; i += BLOCK)
        atomicAdd(&acc[inds_2p[i]], y_s[inds_2r[2 * i]] * y_s[inds_2r[2 * i + 1]] * r2[i]);
    __syncthreads();
    float* orow = y_out + (size_t)b * S;
    for (int i = tid; i < S; i += BLOCK) orow[i] = acc[i];
}

extern "C" void kernel_launch(void* const* d_in, const int* in_sizes, int n_in,
                              void* d_out, int out_size, void* d_ws, size_t ws_size,
                              hipStream_t stream) {
    const float* y_in    = (const float*)d_in[0];
    const float* rate_1  = (const float*)d_in[1];
    const float* rate_2  = (const float*)d_in[2];
    const int*   inds_1r = (const int*)d_in[3];
    const int*   inds_1p = (const int*)d_in[4];
    const int*   inds_2r = (const int*)d_in[5];
    const int*   inds_2p = (const int*)d_in[6];
    float*       y_out   = (float*)d_out;

    const int N1 = in_sizes[3];           // 4096
    const int N2 = in_sizes[6];           // 16384
    const int B  = in_sizes[1] / N1;      // 4096
    const int S  = in_sizes[0] / B;       // 1024

    const bool specialized = (S == 1024 && N1 == 4096 && N2 == 16384 &&
                              (B % 4) == 0 && ws_size >= (size_t)(80 * 1024));
    if (!specialized) {
        size_t smem = (size_t)2 * S * sizeof(float);
        reaction_fallback<256><<<B, 256, smem, stream>>>(
            y_in, rate_1, rate_2, inds_1r, inds_1p, inds_2r, inds_2p,
            y_out, S, N1, N2);
        return;
    }

    // Workspace:
    //   segpack : 10240 u32 [ 0K, 40K)  (10 chunks; start | n<<16)
    //   pos1    :  4096 u16 [40K, 48K)  (chunk-local swizzled positions)
    //   pos2    : 16384 u16 [48K, 80K)
    char* ws = (char*)d_ws;
    unsigned*       segpack = (unsigned*)(ws + 0);
    unsigned short* pos1    = (unsigned short*)(ws + 40 * 1024);
    unsigned short* pos2    = (unsigned short*)(ws + 48 * 1024);

    setup_kernel<<<10, 1024, 0, stream>>>(inds_1p, inds_2p, pos1, pos2, segpack);
    reaction_gather4<<<B / 4, 1024, 0, stream>>>(y_in, rate_1, rate_2,
                                                 inds_1r, inds_2r, pos1, pos2,
                                                 segpack, y_out);
}